// Round 7
// baseline (239.493 us; speedup 1.0000x reference)
//
#include <hip/hip_runtime.h>

#define SC 256   // coarse samples per ray
#define NF 128   // fine (importance) samples per ray

// ---------- DPP helpers (VALU cross-lane; avoids ds_bpermute LDS-pipe ops) ----------
template<int CTRL, int RM, int BM>
__device__ __forceinline__ float dpp_add(float x) {
    int s = __builtin_amdgcn_update_dpp(0, __float_as_int(x), CTRL, RM, BM, true);
    return x + __int_as_float(s);
}
template<int CTRL, int RM, int BM>
__device__ __forceinline__ int dpp_imax(int x) {
    int s = __builtin_amdgcn_update_dpp(0, x, CTRL, RM, BM, true);
    return (x > s) ? x : s;
}
template<int CTRL>
__device__ __forceinline__ float dpp_mov0(float x) {   // zero-fill out-of-range lanes
    return __int_as_float(__builtin_amdgcn_update_dpp(0, __float_as_int(x), CTRL, 0xF, 0xF, true));
}
__device__ __forceinline__ float lane_f(float x, int l) {
    return __int_as_float(__builtin_amdgcn_readlane(__float_as_int(x), l));
}

// wave64 inclusive scan: 6 DPP adds (classic GCN sequence), no LDS traffic
__device__ __forceinline__ float wave_incl_scan(float x) {
    x = dpp_add<0x111, 0xF, 0xF>(x);   // row_shr:1
    x = dpp_add<0x112, 0xF, 0xF>(x);   // row_shr:2
    x = dpp_add<0x114, 0xF, 0xF>(x);   // row_shr:4
    x = dpp_add<0x118, 0xF, 0xF>(x);   // row_shr:8
    x = dpp_add<0x142, 0xA, 0xF>(x);   // row_bcast:15 -> rows 1,3
    x = dpp_add<0x143, 0xC, 0xF>(x);   // row_bcast:31 -> rows 2,3
    return x;
}

// wave64 inclusive MAX-scan (int). 0-fill is a safe identity here: every
// propagated value is >= 0 (position 0 is always written with a bin >= 0).
__device__ __forceinline__ int wave_incl_scan_imax(int x) {
    x = dpp_imax<0x111, 0xF, 0xF>(x);
    x = dpp_imax<0x112, 0xF, 0xF>(x);
    x = dpp_imax<0x114, 0xF, 0xF>(x);
    x = dpp_imax<0x118, 0xF, 0xF>(x);
    x = dpp_imax<0x142, 0xA, 0xF>(x);
    x = dpp_imax<0x143, 0xC, 0xF>(x);
    return x;
}

// reduction valid on lane 0: 4 DPP adds + 3 readlane + 3 adds (zero LDS-pipe)
__device__ __forceinline__ float wave_sum_lane0(float x) {
    x = dpp_add<0xB1, 0xF, 0xF>(x);    // quad_perm(1,0,3,2)  xor1
    x = dpp_add<0x4E, 0xF, 0xF>(x);    // quad_perm(2,3,0,1)  xor2
    x = dpp_add<0x124, 0xF, 0xF>(x);   // row_ror:4
    x = dpp_add<0x128, 0xF, 0xF>(x);   // row_ror:8  -> each lane holds its row-of-16 sum
    return x + lane_f(x, 16) + lane_f(x, 32) + lane_f(x, 48);
}

// first sample index landing in a bin starting at cdf value c:
// u_k = (k+0.5)/128  =>  k >= 128*c - 0.5.  fmaf(128,c,-0.5) is EXACT for
// c in [0,1] (result needs <= 23 significand bits), so this reproduces the
// reference's float compare (cdf <= u, side='right') bit-exactly.
__device__ __forceinline__ int bin_klo(float c) {
    int k = (int)ceilf(fmaf(128.0f, c, -0.5f));
    return (k < 0) ? 0 : k;
}

// per-ray register payload (statically indexed -> stays in VGPRs)
struct Ray {
    float4 sc4;
    float2 sf;
    float2 ra, rb, rc;
};

// Register-keepalive pin: an asm USE of every loaded value. The loads feeding
// these registers must complete before this point (data dependence), so the
// compiler cannot sink them to their uses (which it did in R5: VGPR_Count=24,
// loads issued inside phase3 -> 1-2 loads in flight per wave -> 1.9 TB/s MLP
// ceiling). "+v" makes the pinned register the source of truth (no re-load).
#define PIN_RAY(r)                                                       \
    asm volatile("" : "+v"((r).sc4.x), "+v"((r).sc4.y), "+v"((r).sc4.z), \
                      "+v"((r).sc4.w), "+v"((r).sf.x),  "+v"((r).sf.y),  \
                      "+v"((r).ra.x),  "+v"((r).ra.y),  "+v"((r).rb.x),  \
                      "+v"((r).rb.y),  "+v"((r).rc.x),  "+v"((r).rc.y))

__device__ __forceinline__ Ray load_ray(const float* __restrict__ sig_c,
                                        const float* __restrict__ sig_f,
                                        const float* __restrict__ rgb_f,
                                        int ray, int lane) {
    Ray d;
    d.sc4 = *reinterpret_cast<const float4*>(sig_c + (size_t)ray * SC + 4 * lane);
    d.sf  = *reinterpret_cast<const float2*>(sig_f + (size_t)ray * NF + 2 * lane);
    const float2* rp = reinterpret_cast<const float2*>(rgb_f + (size_t)ray * (NF * 3) + 6 * lane);
    d.ra = rp[0]; d.rb = rp[1]; d.rc = rp[2];
    return d;
}

// ---- phase 1: coarse weights -> reweight -> normalized CDF -> LDS publish +
//      segment-head scatter.
__device__ __forceinline__ void phase1(const Ray& rd, int lane,
                                       float* __restrict__ cdf,
                                       int* __restrict__ idx) {
    const float DLT = 0.015625f;
    float x0 = rd.sc4.x * DLT;
    float x1 = rd.sc4.y * DLT;
    float x2 = rd.sc4.z * DLT;
    float x3 = (lane == 63) ? 0.0f : rd.sc4.w * DLT;   // last delta = 0

    float p0 = x0, p1 = p0 + x1, p2 = p1 + x2, p3 = p2 + x3;
    float incl = wave_incl_scan(p3);
    float excl = incl - p3;

    float T0 = __expf(-excl);
    float T1 = __expf(-(excl + p0));
    float T2 = __expf(-(excl + p1));
    float T3 = __expf(-(excl + p2));
    float T4 = __expf(-(excl + p3));
    float w0 = T0 - T1, w1 = T1 - T2, w2 = T2 - T3, w3 = T3 - T4;

    float wl = dpp_mov0<0x138>(w3);   // wave_shr:1
    float wr = dpp_mov0<0x130>(w0);   // wave_shl:1

    const float FLOOR = 0.01f / 256.0f;
    float m01 = fmaxf(w0, w1), m12 = fmaxf(w1, w2), m23 = fmaxf(w2, w3);
    float r0 = 0.5f * (fmaxf(wl, w0) + m01) + FLOOR;
    float r1 = 0.5f * (m01 + m12) + FLOOR;
    float r2 = 0.5f * (m12 + m23) + FLOOR;
    float r3 = 0.5f * (m23 + fmaxf(w3, wr)) + FLOOR;

    float q0 = r0, q1 = q0 + r1, q2 = q1 + r2, q3 = q2 + r3;
    float incl2 = wave_incl_scan(q3);
    float excl2 = incl2 - q3;
    float total = lane_f(incl2, 63);
    float inv_total = __builtin_amdgcn_rcpf(total);

    float c0 = (excl2 + q0) * inv_total;
    float c1 = (excl2 + q1) * inv_total;
    float c2 = (excl2 + q2) * inv_total;
    float c3 = (excl2 + q3) * inv_total;
    float cprev = dpp_mov0<0x138>(c3);   // lane0 <- 0.0 (exact left boundary)

    *reinterpret_cast<float4*>(&cdf[4 * lane]) = make_float4(c0, c1, c2, c3);
    *reinterpret_cast<int2*>(&idx[2 * lane]) = make_int2(-1, -1);

    // segment-head scatter: nonempty bin j writes its index at its first
    // sample position; nonempty bins have strictly increasing klo -> no
    // collisions; first nonempty bin provably writes position 0.
    const int jb = 4 * lane;
    int k0 = bin_klo(cprev);
    int k1 = bin_klo(c0);
    int k2 = bin_klo(c1);
    int k3 = bin_klo(c2);
    int k4 = bin_klo(c3);
    if (k0 < k1 && k0 < NF) idx[k0] = jb + 0;
    if (k1 < k2 && k1 < NF) idx[k1] = jb + 1;
    if (k2 < k3 && k2 < NF) idx[k2] = jb + 2;
    if (k3 < k4 && k3 < NF) idx[k3] = jb + 3;
}

// ---- phase 2: read heads, propagate with register max-scan, inverse-CDF lerp.
__device__ __forceinline__ float2 phase2(int lane,
                                         const float* __restrict__ cdf,
                                         const int* __restrict__ idx) {
    const float DLT = 0.015625f;
    const int2 jraw = *reinterpret_cast<const int2*>(&idx[2 * lane]);
    int m  = (jraw.x > jraw.y) ? jraw.x : jraw.y;
    int M  = wave_incl_scan_imax(m);
    int E  = __builtin_amdgcn_update_dpp(0, M, 0x138, 0xF, 0xF, true); // excl shr:1
    int j0 = (E  > jraw.x) ? E  : jraw.x;
    int j1 = (j0 > jraw.y) ? j0 : jraw.y;

    int b0 = (j0 > 0) ? j0 - 1 : 0;
    int b1 = (j1 > 0) ? j1 - 1 : 0;
    float ca0 = cdf[j0], cb0 = cdf[b0];
    float ca1 = cdf[j1], cb1 = cdf[b1];

    const float u0 = ((float)(2 * lane) + 0.5f) * 0.0078125f;
    const float u1 = ((float)(2 * lane) + 1.5f) * 0.0078125f;

    float dn0 = ca0 - cb0;  dn0 = (dn0 < 1e-5f) ? 1.0f : dn0;
    float dn1 = ca1 - cb1;  dn1 = (dn1 < 1e-5f) ? 1.0f : dn1;
    float sc0f = (j0 > 0) ? DLT : 0.0f;
    float sc1f = (j1 > 0) ? DLT : 0.0f;
    float zL0 = fmaf((float)b0, DLT, -2.0f);
    float zL1 = fmaf((float)b1, DLT, -2.0f);
    float zl0 = fmaf((u0 - cb0) * __builtin_amdgcn_rcpf(dn0), sc0f, zL0);
    float zl1 = fmaf((u1 - cb1) * __builtin_amdgcn_rcpf(dn1), sc1f, zL1);
    return make_float2(zl0, zl1);
}

// ---- phase 3: fine weights, compositing, stores.
__device__ __forceinline__ void phase3(const Ray& rd, float zl0, float zl1,
                                       int ray, int lane,
                                       float bg0, float bg1, float bg2,
                                       float* __restrict__ out, int n_rays) {
    float znext = dpp_mov0<0x130>(zl0);             // wave_shl:1
    float d0 = zl1 - zl0;
    float d1 = (lane == 63) ? 0.0f : (znext - zl1); // last delta = 0

    float y0 = rd.sf.x * d0;
    float y1 = rd.sf.y * d1;
    float ps = y0 + y1;
    float fincl = wave_incl_scan(ps);
    float fexcl = fincl - ps;

    float U0 = __expf(-fexcl);
    float U1 = __expf(-(fexcl + y0));
    float U2 = __expf(-(fexcl + ps));
    float wf0 = U0 - U1, wf1 = U1 - U2;

    // sample 2l rgb = (ra.x, ra.y, rb.x); sample 2l+1 rgb = (rb.y, rc.x, rc.y)
    float img_r = wf0 * rd.ra.x + wf1 * rd.rb.y;
    float img_g = wf0 * rd.ra.y + wf1 * rd.rc.x;
    float img_b = wf0 * rd.rb.x + wf1 * rd.rc.y;
    float wsum  = wf0 + wf1;
    float invd = wf0 * __exp10f(-zl0) + wf1 * __exp10f(-zl1);

    img_r = wave_sum_lane0(img_r);
    img_g = wave_sum_lane0(img_g);
    img_b = wave_sum_lane0(img_b);
    wsum  = wave_sum_lane0(wsum);
    invd  = wave_sum_lane0(invd);

    float* out_img  = out;
    float* out_invd = out + (size_t)n_rays * 3;
    float* out_wf   = out + (size_t)n_rays * 4;
    float* out_zs   = out + (size_t)n_rays * 4 + (size_t)n_rays * NF;

    if (lane == 0) {
        float one_m = 1.0f - wsum;
        out_img[(size_t)ray * 3 + 0] = img_r + one_m * bg0;
        out_img[(size_t)ray * 3 + 1] = img_g + one_m * bg1;
        out_img[(size_t)ray * 3 + 2] = img_b + one_m * bg2;
        out_invd[ray] = invd;
    }
    *reinterpret_cast<float2*>(out_wf + (size_t)ray * NF + 2 * lane) =
        make_float2(wf0, wf1);
    *reinterpret_cast<float2*>(out_zs + (size_t)ray * NF + 2 * lane) =
        make_float2((zl0 + 2.0f) * 0.25f, (zl1 + 2.0f) * 0.25f);
}

__global__ __launch_bounds__(256) void nerf_render_kernel(
    const float* __restrict__ sig_c,   // [N, 256]
    const float* __restrict__ sig_f,   // [N, 128]
    const float* __restrict__ rgb_f,   // [N, 128, 3]
    const float* __restrict__ bg,      // [3]
    float* __restrict__ out,           // image|invdepth|w_fine|z_log_s concat
    int n_rays)
{
    const int lane = threadIdx.x & 63;
    const int wid  = threadIdx.x >> 6;          // wave within block

    // two rays per wave -> two independent LDS buffers per wave
    __shared__ float s_cdf[8][SC];
    __shared__ int   s_idx[8][NF];

    const int w  = (int)(blockIdx.x << 2) + wid;
    const int rA = 2 * w;
    const int rB = 2 * w + 1;
    if (rA >= n_rays) return;
    const int last = n_rays - 1;

    // issue ALL global loads for both rays up front (10 loads, 6 KB/wave in
    // flight), then force completion with register pins so the compiler
    // cannot sink the loads back to their uses:
    //   PIN(A) -> s_waitcnt vmcnt(5)  (A's 5 loads done, B's still in flight)
    //   PIN(B) -> after phase1(A)'s ~600cy of compute: B latency fully hidden
    Ray A = load_ray(sig_c, sig_f, rgb_f, rA, lane);
    Ray B = load_ray(sig_c, sig_f, rgb_f, rB <= last ? rB : last, lane);
    const float bg0 = bg[0], bg1 = bg[1], bg2 = bg[2];

    float* cdfA = s_cdf[2 * wid + 0];  int* idxA = s_idx[2 * wid + 0];
    float* cdfB = s_cdf[2 * wid + 1];  int* idxB = s_idx[2 * wid + 1];

    PIN_RAY(A);
    phase1(A, lane, cdfA, idxA);
    PIN_RAY(B);
    phase1(B, lane, cdfB, idxB);

    __asm__ __volatile__("" ::: "memory");   // compiler ordering fence only

    float2 zA = phase2(lane, cdfA, idxA);
    float2 zB = phase2(lane, cdfB, idxB);

    phase3(A, zA.x, zA.y, rA, lane, bg0, bg1, bg2, out, n_rays);
    if (rB <= last)
        phase3(B, zB.x, zB.y, rB, lane, bg0, bg1, bg2, out, n_rays);
}

extern "C" void kernel_launch(void* const* d_in, const int* in_sizes, int n_in,
                              void* d_out, int out_size, void* d_ws, size_t ws_size,
                              hipStream_t stream) {
    const float* sig_c = (const float*)d_in[0];
    const float* sig_f = (const float*)d_in[1];
    const float* rgb_f = (const float*)d_in[2];
    const float* bg    = (const float*)d_in[3];
    float* out = (float*)d_out;

    const int n_rays = in_sizes[1] / NF;   // 65536
    const int n_waves = (n_rays + 1) / 2;  // 2 rays per wave
    dim3 grid((n_waves + 3) / 4), block(256);
    hipLaunchKernelGGL(nerf_render_kernel, grid, block, 0, stream,
                       sig_c, sig_f, rgb_f, bg, out, n_rays);
}

// Round 9
// 235.136 us; speedup vs baseline: 1.0185x; 1.0185x over previous
//
#include <hip/hip_runtime.h>

#define SC 256   // coarse samples per ray
#define NF 128   // fine (importance) samples per ray

// ---------- DPP helpers (VALU cross-lane; avoids ds_bpermute LDS-pipe ops) ----------
template<int CTRL, int RM, int BM>
__device__ __forceinline__ float dpp_add(float x) {
    int s = __builtin_amdgcn_update_dpp(0, __float_as_int(x), CTRL, RM, BM, true);
    return x + __int_as_float(s);
}
template<int CTRL>
__device__ __forceinline__ float dpp_mov0(float x) {   // zero-fill out-of-range lanes
    return __int_as_float(__builtin_amdgcn_update_dpp(0, __float_as_int(x), CTRL, 0xF, 0xF, true));
}
__device__ __forceinline__ float lane_f(float x, int l) {
    return __int_as_float(__builtin_amdgcn_readlane(__float_as_int(x), l));
}

// wave64 inclusive scan: 6 DPP adds (classic GCN sequence), no LDS traffic
__device__ __forceinline__ float wave_incl_scan(float x) {
    x = dpp_add<0x111, 0xF, 0xF>(x);   // row_shr:1
    x = dpp_add<0x112, 0xF, 0xF>(x);   // row_shr:2
    x = dpp_add<0x114, 0xF, 0xF>(x);   // row_shr:4
    x = dpp_add<0x118, 0xF, 0xF>(x);   // row_shr:8
    x = dpp_add<0x142, 0xA, 0xF>(x);   // row_bcast:15 -> rows 1,3
    x = dpp_add<0x143, 0xC, 0xF>(x);   // row_bcast:31 -> rows 2,3
    return x;
}

// reduction valid on lane 0: 4 DPP adds + 3 readlane + 3 adds (zero LDS-pipe)
__device__ __forceinline__ float wave_sum_lane0(float x) {
    x = dpp_add<0xB1, 0xF, 0xF>(x);    // quad_perm(1,0,3,2)  xor1
    x = dpp_add<0x4E, 0xF, 0xF>(x);    // quad_perm(2,3,0,1)  xor2
    x = dpp_add<0x124, 0xF, 0xF>(x);   // row_ror:4
    x = dpp_add<0x128, 0xF, 0xF>(x);   // row_ror:8  -> each lane holds its row-of-16 sum
    return x + lane_f(x, 16) + lane_f(x, 32) + lane_f(x, 48);
}

__global__ __launch_bounds__(256) void nerf_render_kernel(
    const float* __restrict__ sig_c,   // [N, 256]
    const float* __restrict__ sig_f,   // [N, 128]
    const float* __restrict__ rgb_f,   // [N, 128, 3]
    const float* __restrict__ bg,      // [3]
    float* __restrict__ out,           // image|invdepth|w_fine|z_log_s concat
    int n_rays)
{
    const int lane = threadIdx.x & 63;
    const int wid  = threadIdx.x >> 6;          // wave (= ray) within block
    const int ray  = (blockIdx.x << 2) + wid;
    if (ray >= n_rays) return;

    __shared__ float s_cdf[4][SC];

    // ---------------- coarse-pass load ----------------
    const float4 sc4 = *reinterpret_cast<const float4*>(sig_c + (size_t)ray * SC + 4 * lane);

    // ---------------- HOIST: issue fine-pass loads NOW ----------------
    // R0's codegen (VGPR=16) sank these to the epilogue, exposing ~900cy of
    // HBM latency AFTER the binary search. Issued here, they complete under
    // the search's ~2000cy dependent-LDS chain. The sched_barrier below
    // pins them above the search.
    const float2 sf  = *reinterpret_cast<const float2*>(sig_f + (size_t)ray * NF + 2 * lane);
    const float2* rp = reinterpret_cast<const float2*>(rgb_f + (size_t)ray * (NF * 3) + 6 * lane);
    const float2 ra = rp[0], rb = rp[1], rc = rp[2];
    const float bg0 = bg[0], bg1 = bg[1], bg2 = bg[2];

    // ---------------- coarse pass: weights on uniform log grid ----------------
    // z_log[j] = -2 + j/64 exactly; delta = 1/64 except last (=0)
    const float DLT = 0.015625f;
    float x0 = sc4.x * DLT;
    float x1 = sc4.y * DLT;
    float x2 = sc4.z * DLT;
    float x3 = (lane == 63) ? 0.0f : sc4.w * DLT;   // last delta = 0

    float p0 = x0, p1 = p0 + x1, p2 = p1 + x2, p3 = p2 + x3;
    float incl = wave_incl_scan(p3);
    float excl = incl - p3;                          // cum before this lane's 1st sample

    // transmittance at sample boundaries; w_j = T_j - T_{j+1}
    float T0 = __expf(-excl);
    float T1 = __expf(-(excl + p0));
    float T2 = __expf(-(excl + p1));
    float T3 = __expf(-(excl + p2));
    float T4 = __expf(-(excl + p3));
    float w0 = T0 - T1, w1 = T1 - T2, w2 = T2 - T3, w3 = T3 - T4;

    // ---------------- reweight: 3-tap max blur + floor (seg scale cancels) ----
    float wl = dpp_mov0<0x138>(w3);   // wave_shr:1 : lane i <- lane i-1, lane0 <- 0
    float wr = dpp_mov0<0x130>(w0);   // wave_shl:1 : lane i <- lane i+1, lane63 <- 0

    const float FLOOR = 0.01f / 256.0f;
    float m01 = fmaxf(w0, w1), m12 = fmaxf(w1, w2), m23 = fmaxf(w2, w3);
    float r0 = 0.5f * (fmaxf(wl, w0) + m01) + FLOOR;
    float r1 = 0.5f * (m01 + m12) + FLOOR;
    float r2 = 0.5f * (m12 + m23) + FLOOR;
    float r3 = 0.5f * (m23 + fmaxf(w3, wr)) + FLOOR;

    // ---------------- normalized CDF into LDS ----------------
    float q0 = r0, q1 = q0 + r1, q2 = q1 + r2, q3 = q2 + r3;
    float incl2 = wave_incl_scan(q3);
    float excl2 = incl2 - q3;
    float total = lane_f(incl2, 63);
    float inv_total = __builtin_amdgcn_rcpf(total);

    *reinterpret_cast<float4*>(&s_cdf[wid][4 * lane]) = make_float4(
        (excl2 + q0) * inv_total, (excl2 + q1) * inv_total,
        (excl2 + q2) * inv_total, (excl2 + q3) * inv_total);

    __syncthreads();

    // scheduler fence: nothing (in particular the sf/ra/rb/rc loads above)
    // may be moved below this point -> their latency hides under the search.
    __builtin_amdgcn_sched_barrier(0);

    // ---------------- inverse-CDF sampling (searchsorted right + lerp) --------
    const float* cdf = s_cdf[wid];
    float zl[2];
    #pragma unroll
    for (int s = 0; s < 2; ++s) {
        const int k = 2 * lane + s;
        const float u = ((float)k + 0.5f) * (1.0f / 128.0f);
        // pos = count of cdf entries <= u  (searchsorted side='right')
        int pos = 0;
        #pragma unroll
        for (int step = 128; step >= 1; step >>= 1) {
            if (cdf[pos + step - 1] <= u) pos += step;   // max idx touched = 254
        }
        int below = pos - 1; if (below < 0) below = 0;
        int above = pos;     if (above > SC - 1) above = SC - 1;
        float cdf_b = cdf[below];
        float cdf_a = cdf[above];
        float bin_b = -2.0f + (float)below * 0.015625f;
        float bin_a = -2.0f + (float)above * 0.015625f;
        float dn = cdf_a - cdf_b;
        dn = (dn < 1e-5f) ? 1.0f : dn;
        float t = (u - cdf_b) / dn;
        zl[s] = bin_b + t * (bin_a - bin_b);
    }
    float zl0 = zl[0], zl1 = zl[1];

    // ---------------- fine pass: weights on sampled grid ----------------
    float znext = dpp_mov0<0x130>(zl0);             // wave_shl:1 -> next lane's first z
    float d0 = zl1 - zl0;
    float d1 = (lane == 63) ? 0.0f : (znext - zl1); // last delta = 0

    float y0 = sf.x * d0;
    float y1 = sf.y * d1;
    float ps = y0 + y1;
    float fincl = wave_incl_scan(ps);
    float fexcl = fincl - ps;

    float U0 = __expf(-fexcl);
    float U1 = __expf(-(fexcl + y0));
    float U2 = __expf(-(fexcl + ps));
    float wf0 = U0 - U1, wf1 = U1 - U2;

    // ---------------- compositing ----------------
    // sample 2l rgb = (ra.x, ra.y, rb.x); sample 2l+1 rgb = (rb.y, rc.x, rc.y)
    float img_r = wf0 * ra.x + wf1 * rb.y;
    float img_g = wf0 * ra.y + wf1 * rc.x;
    float img_b = wf0 * rb.x + wf1 * rc.y;
    float wsum  = wf0 + wf1;
    // 1/z = 10^(-z_log): no divide needed
    float invd = wf0 * __exp10f(-zl0) + wf1 * __exp10f(-zl1);

    img_r = wave_sum_lane0(img_r);
    img_g = wave_sum_lane0(img_g);
    img_b = wave_sum_lane0(img_b);
    wsum  = wave_sum_lane0(wsum);
    invd  = wave_sum_lane0(invd);

    // ---------------- outputs ----------------
    float* out_img  = out;
    float* out_invd = out + (size_t)n_rays * 3;
    float* out_wf   = out + (size_t)n_rays * 4;
    float* out_zs   = out + (size_t)n_rays * 4 + (size_t)n_rays * NF;

    if (lane == 0) {
        float one_m = 1.0f - wsum;
        out_img[(size_t)ray * 3 + 0] = img_r + one_m * bg0;
        out_img[(size_t)ray * 3 + 1] = img_g + one_m * bg1;
        out_img[(size_t)ray * 3 + 2] = img_b + one_m * bg2;
        out_invd[ray] = invd;
    }
    *reinterpret_cast<float2*>(out_wf + (size_t)ray * NF + 2 * lane) =
        make_float2(wf0, wf1);
    *reinterpret_cast<float2*>(out_zs + (size_t)ray * NF + 2 * lane) =
        make_float2((zl0 + 2.0f) * 0.25f, (zl1 + 2.0f) * 0.25f);
}

extern "C" void kernel_launch(void* const* d_in, const int* in_sizes, int n_in,
                              void* d_out, int out_size, void* d_ws, size_t ws_size,
                              hipStream_t stream) {
    const float* sig_c = (const float*)d_in[0];
    const float* sig_f = (const float*)d_in[1];
    const float* rgb_f = (const float*)d_in[2];
    const float* bg    = (const float*)d_in[3];
    float* out = (float*)d_out;

    const int n_rays = in_sizes[1] / NF;   // 65536
    dim3 grid((n_rays + 3) / 4), block(256);
    hipLaunchKernelGGL(nerf_render_kernel, grid, block, 0, stream,
                       sig_c, sig_f, rgb_f, bg, out, n_rays);
}